// Round 2
// baseline (204.458 us; speedup 1.0000x reference)
//
#include <hip/hip_runtime.h>

#define N_NODES 100000
#define HIDDEN 128
#define N_ARCS 1000000

typedef __attribute__((ext_vector_type(8))) short bf16x8;
typedef __attribute__((ext_vector_type(4))) float f32x4;

__device__ __forceinline__ unsigned short f2bf(float v) {
    union { float f; unsigned ui; } c; c.f = v;
    unsigned lsb = (c.ui >> 16) & 1;
    return (unsigned short)((c.ui + 0x7fffu + lsb) >> 16);
}

__device__ __forceinline__ float bf2f(unsigned short x) {
    union { unsigned u; float f; } c; c.u = ((unsigned)x) << 16; return c.f;
}

__device__ __forceinline__ uint4 pack8(float f0, float f1, float f2, float f3,
                                       float f4, float f5, float f6, float f7) {
    uint4 r;
    r.x = (unsigned)f2bf(f0) | ((unsigned)f2bf(f1) << 16);
    r.y = (unsigned)f2bf(f2) | ((unsigned)f2bf(f3) << 16);
    r.z = (unsigned)f2bf(f4) | ((unsigned)f2bf(f5) << 16);
    r.w = (unsigned)f2bf(f6) | ((unsigned)f2bf(f7) << 16);
    return r;
}

// UV[node][0:128] = z @ W1[:, :128]^T ; UV[node][128:256] = z @ W1[:, 128:]^T
// Inputs fp32; converted to bf16 during LDS staging; MFMA bf16; UV stored bf16.
// blockIdx.y selects which 128-column half of W1 (and of UV).
__global__ __launch_bounds__(256) void gemm_uv(const float* __restrict__ z,
                                               const float* __restrict__ W1,
                                               unsigned short* __restrict__ UV) {
    __shared__ unsigned short As[128 * 128];
    __shared__ unsigned short Bs[128 * 128];
    const int tid = threadIdx.x;
    const int m0 = blockIdx.x * 128;
    const int c0 = blockIdx.y * 128;   // 0 -> U half, 128 -> V half

    // Stage A (z tile, fp32 -> bf16), 16B bf16 granules, XOR-swizzled.
    for (int i = tid; i < 2048; i += 256) {
        int row = i >> 4, g = i & 15;
        int node = m0 + row;
        uint4 p = make_uint4(0u, 0u, 0u, 0u);
        if (node < N_NODES) {
            const float4* s = (const float4*)(z + (long)node * 128 + g * 8);
            float4 a = s[0], b = s[1];
            p = pack8(a.x, a.y, a.z, a.w, b.x, b.y, b.z, b.w);
        }
        ((uint4*)As)[row * 16 + (g ^ ((row & 7) << 1))] = p;
    }
    // Stage B: Bs[n][k] = W1[n][c0 + k], fp32 -> bf16.
    for (int i = tid; i < 2048; i += 256) {
        int row = i >> 4, g = i & 15;
        const float4* s = (const float4*)(W1 + (long)row * 256 + c0 + g * 8);
        float4 a = s[0], b = s[1];
        ((uint4*)Bs)[row * 16 + (g ^ ((row & 7) << 1))] =
            pack8(a.x, a.y, a.z, a.w, b.x, b.y, b.z, b.w);
    }
    __syncthreads();

    const int lane = tid & 63;
    const int wave = tid >> 6;
    const int wm = (wave & 1) * 64;
    const int wn = (wave >> 1) * 64;
    const int l16 = lane & 15;
    const int quad = lane >> 4;
    const int sw = (l16 & 7) << 1;

    f32x4 acc[4][4] = {};
    #pragma unroll
    for (int kk = 0; kk < 128; kk += 32) {
        const int gbase = (kk >> 3) + quad;
        bf16x8 a[4], b[4];
        #pragma unroll
        for (int mt = 0; mt < 4; mt++) {
            int row = wm + mt * 16 + l16;
            a[mt] = *(const bf16x8*)&As[row * 128 + ((gbase ^ sw) << 3)];
        }
        #pragma unroll
        for (int nt = 0; nt < 4; nt++) {
            int row = wn + nt * 16 + l16;
            b[nt] = *(const bf16x8*)&Bs[row * 128 + ((gbase ^ sw) << 3)];
        }
        #pragma unroll
        for (int mt = 0; mt < 4; mt++)
            #pragma unroll
            for (int nt = 0; nt < 4; nt++)
                acc[mt][nt] = __builtin_amdgcn_mfma_f32_16x16x32_bf16(
                    a[mt], b[nt], acc[mt][nt], 0, 0, 0);
    }

    // C/D layout: col = lane&15, row = quad*4 + reg
    #pragma unroll
    for (int mt = 0; mt < 4; mt++) {
        #pragma unroll
        for (int nt = 0; nt < 4; nt++) {
            #pragma unroll
            for (int r = 0; r < 4; r++) {
                int grow = m0 + wm + mt * 16 + quad * 4 + r;
                if (grow < N_NODES) {
                    int gcol = c0 + wn + nt * 16 + l16;
                    UV[(long)grow * 256 + gcol] = f2bf(acc[mt][nt][r]);
                }
            }
        }
    }
}

// One arc per 32-lane half-wave: 32 lanes x 4 elems = 128-dim hidden.
// UV bf16; b1/W2/b2/out fp32.
__global__ __launch_bounds__(256) void arc_score(const int2* __restrict__ arcs,
                                                 const unsigned short* __restrict__ UV,
                                                 const float* __restrict__ b1,
                                                 const float* __restrict__ W2,
                                                 const float* __restrict__ b2,
                                                 float* __restrict__ out) {
    const int tid = threadIdx.x;
    const int lane = tid & 63;
    const int sub = lane & 31;
    const int half = lane >> 5;
    const int gw = blockIdx.x * 4 + (tid >> 6);
    const int eb = sub * 4;

    float b1v[4], w2v[4];
    #pragma unroll
    for (int i = 0; i < 4; i++) {
        b1v[i] = b1[eb + i];
        w2v[i] = W2[eb + i];
    }
    const float b2s = b2[0];

    const int stride = gridDim.x * 8;   // 4 waves/block * 2 arcs/wave
    for (int a = gw * 2 + half; a < N_ARCS; a += stride) {
        int2 sd = arcs[a];
        const ushort4 u = *(const ushort4*)(UV + (long)sd.x * 256 + eb);
        const ushort4 v = *(const ushort4*)(UV + (long)sd.y * 256 + 128 + eb);
        float h0 = fmaxf(bf2f(u.x) + bf2f(v.x) + b1v[0], 0.f);
        float h1 = fmaxf(bf2f(u.y) + bf2f(v.y) + b1v[1], 0.f);
        float h2 = fmaxf(bf2f(u.z) + bf2f(v.z) + b1v[2], 0.f);
        float h3 = fmaxf(bf2f(u.w) + bf2f(v.w) + b1v[3], 0.f);
        float p = h0 * w2v[0] + h1 * w2v[1] + h2 * w2v[2] + h3 * w2v[3];
        #pragma unroll
        for (int o = 16; o >= 1; o >>= 1) p += __shfl_xor(p, o);
        if (sub == 0) out[a] = p + b2s;
    }
}

extern "C" void kernel_launch(void* const* d_in, const int* in_sizes, int n_in,
                              void* d_out, int out_size, void* d_ws, size_t ws_size,
                              hipStream_t stream) {
    const float* z  = (const float*)d_in[0];
    const int2* arcs = (const int2*)d_in[1];
    const float* W1 = (const float*)d_in[2];
    const float* b1 = (const float*)d_in[3];
    const float* W2 = (const float*)d_in[4];
    const float* b2 = (const float*)d_in[5];
    float* out = (float*)d_out;

    // Workspace: UV bf16 [100000][256] = 51.2 MB
    unsigned short* UV = (unsigned short*)d_ws;

    hipLaunchKernelGGL(gemm_uv, dim3((N_NODES + 127) / 128, 2), dim3(256), 0, stream,
                       z, W1, UV);
    hipLaunchKernelGGL(arc_score, dim3(2048), dim3(256), 0, stream,
                       arcs, UV, b1, W2, b2, out);
}